// Round 6
// baseline (105.632 us; speedup 1.0000x reference)
//
#include <hip/hip_runtime.h>
#include <math.h>

#define NCLS 1000
#define NF4  250     // float4s per row
#define TPB  256
#define WPB  4       // waves per block
#define RPW  2       // rows per wave
#define RPB  (WPB * RPW)

#if __has_builtin(__builtin_amdgcn_exp2f)
__device__ __forceinline__ float fast_exp2(float x) { return __builtin_amdgcn_exp2f(x); }
#else
__device__ __forceinline__ float fast_exp2(float x) { return exp2f(x); }
#endif

// ---------------------------------------------------------------------------
// cum[k-1] for the uniform row per jax.lax.associative_scan (tree) order.
// Verified bit-exact in R3/R4/R5 (absmax == 0.0).
// ---------------------------------------------------------------------------
__device__ __forceinline__ float scan_val(int k) {
    const unsigned xb = __float_as_uint(0.001f);
    const int hb = 31 - __clz(k);
    float acc = __uint_as_float(xb + ((unsigned)hb << 23));  // x * 2^hb, exact
    #pragma unroll 1
    for (int l = hb - 1; l >= 0; --l) {
        if (k & (1u << l)) {
            const float t = __uint_as_float(xb + ((unsigned)l << 23)); // x*2^l
            acc += t;
            asm volatile("" : "+v"(acc));
        }
    }
    return acc;
}

// ---------------------------------------------------------------------------
// idx = #{i in [0,999]: T[i] < th}, T[i] = scan_val(i+1).
// T is strictly monotone with |T[k-1] - k*0.001| <= ~7e-7, so only a +/-3
// window around floor(th*1000) can flip; outside it the compare is decided
// by a >= 0.002 margin. Comparisons use the exact scan_val bits -> result is
// bit-identical to the full 1000-entry count of R3/R5.
// ---------------------------------------------------------------------------
__device__ __forceinline__ int count_below(float th) {
    int ke = (int)(th * 1000.0f);
    int lo = ke - 3; if (lo < 1) lo = 1;
    int hi = ke + 3; if (hi > 1000) hi = 1000;
    int cnt = lo - 1;                 // all k < lo satisfy scan_val(k) < th
    #pragma unroll 1
    for (int k = lo; k <= hi; ++k)
        cnt += (scan_val(k) < th) ? 1 : 0;
    return cnt;
}

// ---------------------------------------------------------------------------
// Wave-level (64-lane) reductions — pure register butterflies, no barriers.
// ---------------------------------------------------------------------------
__device__ __forceinline__ float wave_max(float v) {
    #pragma unroll
    for (int o = 32; o; o >>= 1) v = fmaxf(v, __shfl_xor(v, o));
    return v;
}
__device__ __forceinline__ float wave_sum(float v) {
    #pragma unroll
    for (int o = 32; o; o >>= 1) v += __shfl_xor(v, o);
    return v;
}
__device__ __forceinline__ int wave_sumi(int v) {
    #pragma unroll
    for (int o = 32; o; o >>= 1) v += __shfl_xor(v, o);
    return v;
}

// ---------------------------------------------------------------------------
// One WAVE per TWO rows. No __syncthreads anywhere.
// ---------------------------------------------------------------------------
__global__ __launch_bounds__(TPB) void defence_kernel(
    const float* __restrict__ logits,
    const float* __restrict__ noise,
    const float* __restrict__ u,
    float* __restrict__ out,
    int batch)
{
    const int lane = threadIdx.x & 63;
    const int wid  = threadIdx.x >> 6;
    const int row0 = (blockIdx.x * WPB + wid) * RPW;
    if (row0 >= batch) return;                   // wave-uniform
    const bool has1 = (row0 + 1) < batch;
    const int row1 = has1 ? row0 + 1 : row0;

    __shared__ unsigned char kbuf[RPB][NCLS];    // cold path only

    const float uu0 = u[row0];
    const float uu1 = u[row1];

    const float NEG = -INFINITY;
    const float4* lgA = reinterpret_cast<const float4*>(logits + (size_t)row0 * NCLS);
    const float4* lgB = reinterpret_cast<const float4*>(logits + (size_t)row1 * NCLS);
    const float4* nzA = reinterpret_cast<const float4*>(noise  + (size_t)row0 * NCLS);
    const float4* nzB = reinterpret_cast<const float4*>(noise  + (size_t)row1 * NCLS);

    float4 lvA[4], lvB[4], nvA[4], nvB[4];
    #pragma unroll
    for (int t = 0; t < 4; ++t) {
        const int j = lane + 64 * t;
        const bool a = j < NF4;
        lvA[t] = a ? lgA[j] : make_float4(NEG, NEG, NEG, NEG);
        lvB[t] = a ? lgB[j] : make_float4(NEG, NEG, NEG, NEG);
        nvA[t] = a ? nzA[j] : make_float4(0.f, 0.f, 0.f, 0.f);
        nvB[t] = a ? nzB[j] : make_float4(0.f, 0.f, 0.f, 0.f);
    }

    // Sampling index depends only on u — compute concurrently, no memory.
    const float T999 = scan_val(1000);
    int idxA = count_below(uu0 * T999);          // bit-identical th & compares
    int idxB = count_below(uu1 * T999);

    // ---- fast path pass A: unbiased exp2 (tiny values, no overflow) ----
    const float K6 = 0.2404491734814939f;        // log2(e)/6
    float mA = NEG, sA = 0.f, mB = NEG, sB = 0.f;
    #pragma unroll
    for (int t = 0; t < 4; ++t) {
        mA = fmaxf(mA, fmaxf(fmaxf(lvA[t].x, lvA[t].y), fmaxf(lvA[t].z, lvA[t].w)));
        mB = fmaxf(mB, fmaxf(fmaxf(lvB[t].x, lvB[t].y), fmaxf(lvB[t].z, lvB[t].w)));
        sA += (fast_exp2(lvA[t].x * K6) + fast_exp2(lvA[t].y * K6))
            + (fast_exp2(lvA[t].z * K6) + fast_exp2(lvA[t].w * K6));
        sB += (fast_exp2(lvB[t].x * K6) + fast_exp2(lvB[t].y * K6))
            + (fast_exp2(lvB[t].z * K6) + fast_exp2(lvB[t].w * K6));
    }
    const float m1A = wave_max(mA), m1B = wave_max(mB);   // 4 independent
    const float s1A = wave_sum(sA), s1B = wave_sum(sB);   // shfl chains
    const float mcA = fast_exp2(m1A * K6) / s1A;
    const float mcB = fast_exp2(m1B * K6) / s1B;
    const float sdA = fmaf(0.6f, mcA * mcA, 0.3f);
    const float sdB = fmaf(0.6f, mcB * mcB, 0.3f);

    // ---- fast path pass B ----
    const float L2E = 1.4426950408889634f;
    float m2lA = NEG, s2lA = 0.f, m2lB = NEG, s2lB = 0.f;
    #pragma unroll
    for (int t = 0; t < 4; ++t) {
        const float a0 = fmaf(nvA[t].x, sdA, lvA[t].x * (1.0f / 6.0f));
        const float a1 = fmaf(nvA[t].y, sdA, lvA[t].y * (1.0f / 6.0f));
        const float a2 = fmaf(nvA[t].z, sdA, lvA[t].z * (1.0f / 6.0f));
        const float a3 = fmaf(nvA[t].w, sdA, lvA[t].w * (1.0f / 6.0f));
        m2lA = fmaxf(m2lA, fmaxf(fmaxf(a0, a1), fmaxf(a2, a3)));
        s2lA += (fast_exp2(a0 * L2E) + fast_exp2(a1 * L2E))
              + (fast_exp2(a2 * L2E) + fast_exp2(a3 * L2E));
        const float b0 = fmaf(nvB[t].x, sdB, lvB[t].x * (1.0f / 6.0f));
        const float b1 = fmaf(nvB[t].y, sdB, lvB[t].y * (1.0f / 6.0f));
        const float b2 = fmaf(nvB[t].z, sdB, lvB[t].z * (1.0f / 6.0f));
        const float b3 = fmaf(nvB[t].w, sdB, lvB[t].w * (1.0f / 6.0f));
        m2lB = fmaxf(m2lB, fmaxf(fmaxf(b0, b1), fmaxf(b2, b3)));
        s2lB += (fast_exp2(b0 * L2E) + fast_exp2(b1 * L2E))
              + (fast_exp2(b2 * L2E) + fast_exp2(b3 * L2E));
    }
    const float m2A = wave_max(m2lA), m2B = wave_max(m2lB);
    const float s2A = wave_sum(s2lA), s2B = wave_sum(s2lB);
    const float eA = fast_exp2(m2A * L2E);       // overflow -> inf -> exact path
    const float eB = fast_exp2(m2B * L2E);

    // K==0 <=> max renorm prob <= 0.05; require maxp < 1/22. Data: <= 0.026.
    const bool failA = !(s2A > 22.0f * eA);
    const bool failB = !(s2B > 22.0f * eB);

    if (__builtin_expect(failA || failB, 0)) {
        // ---- exact reference-semantics path (wave-uniform; cold) ----
        #pragma unroll 1
        for (int r = 0; r < RPW; ++r) {
            if (!(r ? failB : failA)) continue;
            float4 xl[4], xn[4];
            #pragma unroll
            for (int t = 0; t < 4; ++t) {
                xl[t] = r ? lvB[t] : lvA[t];
                xn[t] = r ? nvB[t] : nvA[t];
            }
            const float xu = r ? uu1 : uu0;
            unsigned char* kb = kbuf[wid * RPW + r];

            float ml = NEG;
            #pragma unroll
            for (int t = 0; t < 4; ++t)
                ml = fmaxf(ml, fmaxf(fmaxf(xl[t].x, xl[t].y), fmaxf(xl[t].z, xl[t].w)));
            const float m1x = wave_max(ml) / 6.0f;   // div is monotone
            float se1 = 0.f;
            #pragma unroll
            for (int t = 0; t < 4; ++t)
                se1 += expf(xl[t].x / 6.0f - m1x) + expf(xl[t].y / 6.0f - m1x)
                     + expf(xl[t].z / 6.0f - m1x) + expf(xl[t].w / 6.0f - m1x);
            const float s1x = wave_sum(se1);
            const float mcx = 1.0f / s1x;
            const float sdx = 0.3f + 0.6f * (mcx * mcx);

            float m2l = NEG;
            #pragma unroll
            for (int t = 0; t < 4; ++t) {
                const float y0 = xl[t].x / 6.0f + xn[t].x * sdx;
                const float y1 = xl[t].y / 6.0f + xn[t].y * sdx;
                const float y2 = xl[t].z / 6.0f + xn[t].z * sdx;
                const float y3 = xl[t].w / 6.0f + xn[t].w * sdx;
                m2l = fmaxf(m2l, fmaxf(fmaxf(y0, y1), fmaxf(y2, y3)));
            }
            const float m2x = wave_max(m2l);
            float se2 = 0.f;
            #pragma unroll
            for (int t = 0; t < 4; ++t)
                se2 += expf(xl[t].x / 6.0f + xn[t].x * sdx - m2x)
                     + expf(xl[t].y / 6.0f + xn[t].y * sdx - m2x)
                     + expf(xl[t].z / 6.0f + xn[t].z * sdx - m2x)
                     + expf(xl[t].w / 6.0f + xn[t].w * sdx - m2x);
            const float s2x = wave_sum(se2);
            float cs = 0.f;
            #pragma unroll
            for (int t = 0; t < 4; ++t)
                cs += fminf(expf(xl[t].x / 6.0f + xn[t].x * sdx - m2x) / s2x, 0.6f)
                    + fminf(expf(xl[t].y / 6.0f + xn[t].y * sdx - m2x) / s2x, 0.6f)
                    + fminf(expf(xl[t].z / 6.0f + xn[t].z * sdx - m2x) / s2x, 0.6f)
                    + fminf(expf(xl[t].w / 6.0f + xn[t].w * sdx - m2x) / s2x, 0.6f);
            const float rsum = wave_sum(cs);
            int kls = 0;
            #pragma unroll
            for (int t = 0; t < 4; ++t) {
                const int j = lane + 64 * t;
                if (j < NF4) {
                    const float yv[4] = {
                        xl[t].x / 6.0f + xn[t].x * sdx, xl[t].y / 6.0f + xn[t].y * sdx,
                        xl[t].z / 6.0f + xn[t].z * sdx, xl[t].w / 6.0f + xn[t].w * sdx };
                    #pragma unroll
                    for (int c = 0; c < 4; ++c) {
                        const float cl = fminf(expf(yv[c] - m2x) / s2x, 0.6f);
                        const int kk = (int)rintf((cl / rsum) * 10.0f);
                        kb[4 * j + c] = (unsigned char)kk;
                        kls += kk;
                    }
                }
            }
            const int K = wave_sumi(kls);
            int idr;
            if (K == 0) {
                idr = count_below(xu * T999);
            } else {
                asm volatile("s_waitcnt lgkmcnt(0)" ::: "memory");
                __builtin_amdgcn_wave_barrier();
                int cnt = 0;
                if (lane == 0) {
                    const double tab[11] = {0.0, 0.1, 0.2, 0.3, 0.4, 0.5,
                                            0.6, 0.7, 0.8, 0.9, 1.0};
                    double c = 0.0;
                    for (int i = 0; i < NCLS; ++i) c += tab[kb[i]];
                    const double th = (double)xu * c;
                    c = 0.0;
                    for (int i = 0; i < NCLS; ++i) {
                        c += tab[kb[i]];
                        cnt += (c < th) ? 1 : 0;
                    }
                }
                idr = __shfl(cnt, 0);
            }
            if (r) idxB = idr; else idxA = idr;
        }
    }

    // epilogue: log(one_hot*(1-EPS) + EPS/C) — identical expressions to R3-R5
    const float V0 = logf(1e-7f);
    const float V1 = logf(0.9999f + 1e-7f);
    float4* oA = reinterpret_cast<float4*>(out + (size_t)row0 * NCLS);
    float4* oB = reinterpret_cast<float4*>(out + (size_t)row1 * NCLS);
    #pragma unroll
    for (int t = 0; t < 4; ++t) {
        const int j = lane + 64 * t;
        if (j < NF4) {
            const int base = 4 * j;
            float4 ov = {V0, V0, V0, V0};
            if (idxA >= base && idxA < base + 4) (&ov.x)[idxA - base] = V1;
            oA[j] = ov;
            float4 ow = {V0, V0, V0, V0};
            if (idxB >= base && idxB < base + 4) (&ow.x)[idxB - base] = V1;
            if (has1) oB[j] = ow;
        }
    }
}

extern "C" void kernel_launch(void* const* d_in, const int* in_sizes, int n_in,
                              void* d_out, int out_size, void* d_ws, size_t ws_size,
                              hipStream_t stream) {
    const float* logits = (const float*)d_in[0];
    const float* noise  = (const float*)d_in[1];
    const float* u      = (const float*)d_in[2];
    float* out = (float*)d_out;

    const int batch = in_sizes[2];       // 32768 rows (u is [B,1])
    const int blocks = (batch + RPB - 1) / RPB;

    hipLaunchKernelGGL(defence_kernel, dim3(blocks), dim3(TPB), 0, stream,
                       logits, noise, u, out, batch);
}

// Round 7
// 84.760 us; speedup vs baseline: 1.2462x; 1.2462x over previous
//
#include <hip/hip_runtime.h>
#include <math.h>

#define NCLS 1000
#define NF4  250     // float4s per row
#define TPB  256
#define WPB  4       // waves (rows) per block

#if __has_builtin(__builtin_amdgcn_exp2f)
__device__ __forceinline__ float fast_exp2(float x) { return __builtin_amdgcn_exp2f(x); }
#else
__device__ __forceinline__ float fast_exp2(float x) { return exp2f(x); }
#endif

// ---------------------------------------------------------------------------
// cum[k-1] for the uniform row per jax.lax.associative_scan (tree) order.
// Verified bit-exact in R3-R6 (absmax == 0.0).
// ---------------------------------------------------------------------------
__device__ __forceinline__ float scan_val(int k) {
    const unsigned xb = __float_as_uint(0.001f);
    const int hb = 31 - __clz(k);
    float acc = __uint_as_float(xb + ((unsigned)hb << 23));  // x * 2^hb, exact
    #pragma unroll 1
    for (int l = hb - 1; l >= 0; --l) {
        if (k & (1u << l)) {
            const float t = __uint_as_float(xb + ((unsigned)l << 23)); // x*2^l
            acc += t;
            asm volatile("" : "+v"(acc));
        }
    }
    return acc;
}

// ---------------------------------------------------------------------------
// idx = #{k in [1,1000]: scan_val(k) < th}.
// |scan_val(k) - k*0.001| <= ~7e-7 and fma(th,1000,0.5) error <= 6e-5, so
// only k0 = trunc(fma(th,1000,0.5)) is ambiguous; every other k is decided
// by a >= 4.9e-4 margin. Bit-identical to the full count of R3-R6.
// ---------------------------------------------------------------------------
__device__ __forceinline__ int count_below(float th) {
    int k0 = (int)fmaf(th, 1000.0f, 0.5f);
    k0 = (k0 < 1) ? 1 : (k0 > 1000 ? 1000 : k0);
    return (k0 - 1) + ((scan_val(k0) < th) ? 1 : 0);
}

// ---------------------------------------------------------------------------
// Wave-level (64-lane) reductions — pure register butterflies, no barriers.
// ---------------------------------------------------------------------------
__device__ __forceinline__ float wave_max(float v) {
    #pragma unroll
    for (int o = 32; o; o >>= 1) v = fmaxf(v, __shfl_xor(v, o));
    return v;
}
__device__ __forceinline__ float wave_sum(float v) {
    #pragma unroll
    for (int o = 32; o; o >>= 1) v += __shfl_xor(v, o);
    return v;
}
__device__ __forceinline__ int wave_sumi(int v) {
    #pragma unroll
    for (int o = 32; o; o >>= 1) v += __shfl_xor(v, o);
    return v;
}

// ---------------------------------------------------------------------------
// One WAVE per row; store decoupled from the verification chain.
// ---------------------------------------------------------------------------
__global__ __launch_bounds__(TPB, 8) void defence_kernel(
    const float* __restrict__ logits,
    const float* __restrict__ noise,
    const float* __restrict__ u,
    float* __restrict__ out,
    int batch)
{
    const int lane = threadIdx.x & 63;
    const int wid  = threadIdx.x >> 6;
    const int row  = blockIdx.x * WPB + wid;
    if (row >= batch) return;                    // wave-uniform

    __shared__ unsigned char kbuf[WPB][NCLS];    // cold path only

    const float uu = u[row];

    const float NEG = -INFINITY;
    const float4* lg4 = reinterpret_cast<const float4*>(logits + (size_t)row * NCLS);
    const float4* nz4 = reinterpret_cast<const float4*>(noise  + (size_t)row * NCLS);

    // issue ALL row loads up front (8 outstanding dwordx4)
    float4 lv[4], nv[4];
    #pragma unroll
    for (int t = 0; t < 4; ++t) {
        const int j = lane + 64 * t;
        const bool a = j < NF4;
        lv[t] = a ? lg4[j] : make_float4(NEG, NEG, NEG, NEG);
        nv[t] = a ? nz4[j] : make_float4(0.f, 0.f, 0.f, 0.f);
    }

    // ---- sampling index from u alone; store output EARLY (fills the load
    // shadow; the softmax below only verifies K==0 and almost never rewrites)
    const float T999 = scan_val(1000);
    const float th0  = uu * T999;                // bit-identical th
    int idx = count_below(th0);

    const float V0 = logf(1e-7f);                // EPS/C
    const float V1 = logf(0.9999f + 1e-7f);      // (1-EPS) + EPS/C
    float4* o4 = reinterpret_cast<float4*>(out + (size_t)row * NCLS);
    #pragma unroll
    for (int t = 0; t < 4; ++t) {
        const int j = lane + 64 * t;
        if (j < NF4) {
            float4 ov = {V0, V0, V0, V0};
            const int base = 4 * j;
            if (idx >= base && idx < base + 4)
                (&ov.x)[idx - base] = V1;
            o4[j] = ov;
        }
    }

    // ---- fast-path verification: decide K==0 (margin ~2x) ----
    const float K6 = 0.2404491734814939f;        // log2(e)/6
    float mA = NEG, sA = 0.f;
    #pragma unroll
    for (int t = 0; t < 4; ++t) {
        mA = fmaxf(mA, fmaxf(fmaxf(lv[t].x, lv[t].y), fmaxf(lv[t].z, lv[t].w)));
        sA += (fast_exp2(lv[t].x * K6) + fast_exp2(lv[t].y * K6))
            + (fast_exp2(lv[t].z * K6) + fast_exp2(lv[t].w * K6));
    }
    const float m1 = wave_max(mA);               // independent shfl chains
    const float s1 = wave_sum(sA);
    const float mc = fast_exp2(m1 * K6) / s1;    // max softmax#1 prob
    const float sd = fmaf(0.6f, mc * mc, 0.3f);

    const float L2E = 1.4426950408889634f;
    float m2l = NEG, s2l = 0.f;
    #pragma unroll
    for (int t = 0; t < 4; ++t) {
        const float y0 = fmaf(nv[t].x, sd, lv[t].x * (1.0f / 6.0f));
        const float y1 = fmaf(nv[t].y, sd, lv[t].y * (1.0f / 6.0f));
        const float y2 = fmaf(nv[t].z, sd, lv[t].z * (1.0f / 6.0f));
        const float y3 = fmaf(nv[t].w, sd, lv[t].w * (1.0f / 6.0f));
        m2l = fmaxf(m2l, fmaxf(fmaxf(y0, y1), fmaxf(y2, y3)));
        s2l += (fast_exp2(y0 * L2E) + fast_exp2(y1 * L2E))
             + (fast_exp2(y2 * L2E) + fast_exp2(y3 * L2E));
    }
    const float m2  = wave_max(m2l);
    const float s2  = wave_sum(s2l);
    const float e2m = fast_exp2(m2 * L2E);       // overflow/NaN -> exact path

    // K==0 <=> max renorm prob <= 0.05; require maxp < 1/22 = 0.0455.
    // Data margin: maxp <= ~0.026. Boundary rows fall to the exact path.
    if (__builtin_expect(!(s2 > 22.0f * e2m), 0)) {
        // ---- exact reference-semantics path (wave-uniform; cold) ----
        const float m1x = m1 / 6.0f;             // max(l)/6 == max(l/6)
        float se1 = 0.f;
        #pragma unroll
        for (int t = 0; t < 4; ++t)
            se1 += expf(lv[t].x / 6.0f - m1x) + expf(lv[t].y / 6.0f - m1x)
                 + expf(lv[t].z / 6.0f - m1x) + expf(lv[t].w / 6.0f - m1x);
        const float s1x = wave_sum(se1);
        const float mcx = 1.0f / s1x;
        const float sdx = 0.3f + 0.6f * (mcx * mcx);

        float m2xl = NEG;
        #pragma unroll
        for (int t = 0; t < 4; ++t) {
            const float y0 = lv[t].x / 6.0f + nv[t].x * sdx;
            const float y1 = lv[t].y / 6.0f + nv[t].y * sdx;
            const float y2 = lv[t].z / 6.0f + nv[t].z * sdx;
            const float y3 = lv[t].w / 6.0f + nv[t].w * sdx;
            m2xl = fmaxf(m2xl, fmaxf(fmaxf(y0, y1), fmaxf(y2, y3)));
        }
        const float m2x = wave_max(m2xl);
        float se2 = 0.f;
        #pragma unroll
        for (int t = 0; t < 4; ++t)
            se2 += expf(lv[t].x / 6.0f + nv[t].x * sdx - m2x)
                 + expf(lv[t].y / 6.0f + nv[t].y * sdx - m2x)
                 + expf(lv[t].z / 6.0f + nv[t].z * sdx - m2x)
                 + expf(lv[t].w / 6.0f + nv[t].w * sdx - m2x);
        const float s2x = wave_sum(se2);
        float cs = 0.f;
        #pragma unroll
        for (int t = 0; t < 4; ++t)
            cs += fminf(expf(lv[t].x / 6.0f + nv[t].x * sdx - m2x) / s2x, 0.6f)
                + fminf(expf(lv[t].y / 6.0f + nv[t].y * sdx - m2x) / s2x, 0.6f)
                + fminf(expf(lv[t].z / 6.0f + nv[t].z * sdx - m2x) / s2x, 0.6f)
                + fminf(expf(lv[t].w / 6.0f + nv[t].w * sdx - m2x) / s2x, 0.6f);
        const float rsum = wave_sum(cs);
        int kls = 0;
        #pragma unroll
        for (int t = 0; t < 4; ++t) {
            const int j = lane + 64 * t;
            if (j < NF4) {
                const float yv[4] = {
                    lv[t].x / 6.0f + nv[t].x * sdx, lv[t].y / 6.0f + nv[t].y * sdx,
                    lv[t].z / 6.0f + nv[t].z * sdx, lv[t].w / 6.0f + nv[t].w * sdx };
                #pragma unroll
                for (int c = 0; c < 4; ++c) {
                    const float cl = fminf(expf(yv[c] - m2x) / s2x, 0.6f);
                    const int kk = (int)rintf((cl / rsum) * 10.0f);
                    kbuf[wid][4 * j + c] = (unsigned char)kk;
                    kls += kk;
                }
            }
        }
        const int K = wave_sumi(kls);
        int idx2;
        if (K == 0) {
            idx2 = count_below(th0);
        } else {
            asm volatile("s_waitcnt lgkmcnt(0)" ::: "memory");
            __builtin_amdgcn_wave_barrier();
            int cnt = 0;
            if (lane == 0) {
                const double tab[11] = {0.0, 0.1, 0.2, 0.3, 0.4, 0.5,
                                        0.6, 0.7, 0.8, 0.9, 1.0};
                double c = 0.0;
                for (int i = 0; i < NCLS; ++i) c += tab[kbuf[wid][i]];
                const double th = (double)uu * c;
                c = 0.0;
                for (int i = 0; i < NCLS; ++i) {
                    c += tab[kbuf[wid][i]];
                    cnt += (c < th) ? 1 : 0;
                }
            }
            idx2 = __shfl(cnt, 0);
        }
        // rewrite the row with the exact index
        #pragma unroll
        for (int t = 0; t < 4; ++t) {
            const int j = lane + 64 * t;
            if (j < NF4) {
                float4 ov = {V0, V0, V0, V0};
                const int base = 4 * j;
                if (idx2 >= base && idx2 < base + 4)
                    (&ov.x)[idx2 - base] = V1;
                o4[j] = ov;
            }
        }
    }
}

extern "C" void kernel_launch(void* const* d_in, const int* in_sizes, int n_in,
                              void* d_out, int out_size, void* d_ws, size_t ws_size,
                              hipStream_t stream) {
    const float* logits = (const float*)d_in[0];
    const float* noise  = (const float*)d_in[1];
    const float* u      = (const float*)d_in[2];
    float* out = (float*)d_out;

    const int batch = in_sizes[2];       // 32768 rows (u is [B,1])
    const int blocks = (batch + WPB - 1) / WPB;

    hipLaunchKernelGGL(defence_kernel, dim3(blocks), dim3(TPB), 0, stream,
                       logits, noise, u, out, batch);
}

// Round 9
// 70.466 us; speedup vs baseline: 1.4991x; 1.2029x over previous
//
#include <hip/hip_runtime.h>
#include <math.h>

#define NCLS 1000
#define NF4  250     // float4s per row
#define TPB  256
#define WPB  4       // waves (rows) per block

typedef float vfloat4 __attribute__((ext_vector_type(4)));  // NT-builtin-compatible

#if __has_builtin(__builtin_amdgcn_exp2f)
__device__ __forceinline__ float fast_exp2(float x) { return __builtin_amdgcn_exp2f(x); }
#else
__device__ __forceinline__ float fast_exp2(float x) { return exp2f(x); }
#endif

// ---------------------------------------------------------------------------
// cum[k-1] for the uniform row per jax.lax.associative_scan (tree) order.
// Verified bit-exact in R3-R7 (absmax == 0.0).
// ---------------------------------------------------------------------------
__device__ __forceinline__ float scan_val(int k) {
    const unsigned xb = __float_as_uint(0.001f);
    const int hb = 31 - __clz(k);
    float acc = __uint_as_float(xb + ((unsigned)hb << 23));  // x * 2^hb, exact
    #pragma unroll 1
    for (int l = hb - 1; l >= 0; --l) {
        if (k & (1u << l)) {
            const float t = __uint_as_float(xb + ((unsigned)l << 23)); // x*2^l
            acc += t;
            asm volatile("" : "+v"(acc));
        }
    }
    return acc;
}

// ---------------------------------------------------------------------------
// idx = #{k in [1,1000]: scan_val(k) < th}.  Only k0 = trunc(fma(th,1000,.5))
// is ambiguous (margin proof in R7); bit-identical to the full count.
// ---------------------------------------------------------------------------
__device__ __forceinline__ int count_below(float th) {
    int k0 = (int)fmaf(th, 1000.0f, 0.5f);
    k0 = (k0 < 1) ? 1 : (k0 > 1000 ? 1000 : k0);
    return (k0 - 1) + ((scan_val(k0) < th) ? 1 : 0);
}

// ---------------------------------------------------------------------------
// Wave-level (64-lane) reductions — pure register butterflies, no barriers.
// ---------------------------------------------------------------------------
__device__ __forceinline__ float wave_max(float v) {
    #pragma unroll
    for (int o = 32; o; o >>= 1) v = fmaxf(v, __shfl_xor(v, o));
    return v;
}
__device__ __forceinline__ float wave_sum(float v) {
    #pragma unroll
    for (int o = 32; o; o >>= 1) v += __shfl_xor(v, o);
    return v;
}
__device__ __forceinline__ int wave_sumi(int v) {
    #pragma unroll
    for (int o = 32; o; o >>= 1) v += __shfl_xor(v, o);
    return v;
}

// ---------------------------------------------------------------------------
// One WAVE per row; early NT store decoupled from the verification chain.
// ---------------------------------------------------------------------------
__global__ __launch_bounds__(TPB, 8) void defence_kernel(
    const float* __restrict__ logits,
    const float* __restrict__ noise,
    const float* __restrict__ u,
    float* __restrict__ out,
    int batch)
{
    const int lane = threadIdx.x & 63;
    const int wid  = threadIdx.x >> 6;
    const int row  = blockIdx.x * WPB + wid;
    if (row >= batch) return;                    // wave-uniform

    __shared__ unsigned char kbuf[WPB][NCLS];    // cold path only

    const float uu = u[row];

    const float NEG = -INFINITY;
    const vfloat4* lg4 = reinterpret_cast<const vfloat4*>(logits + (size_t)row * NCLS);
    const vfloat4* nz4 = reinterpret_cast<const vfloat4*>(noise  + (size_t)row * NCLS);

    // issue ALL row loads up front, non-temporal (single-use streams: don't
    // allocate L2 lines, leave the cache to the write path)
    vfloat4 lv[4], nv[4];
    #pragma unroll
    for (int t = 0; t < 4; ++t) {
        const int j = lane + 64 * t;
        const bool a = j < NF4;
        if (a) {
            lv[t] = __builtin_nontemporal_load(&lg4[j]);
            nv[t] = __builtin_nontemporal_load(&nz4[j]);
        } else {
            lv[t] = (vfloat4){NEG, NEG, NEG, NEG};
            nv[t] = (vfloat4){0.f, 0.f, 0.f, 0.f};
        }
    }

    // ---- sampling index from u alone; NT-store output EARLY (fills the
    // load shadow; lines never sit dirty in L2 -> no write amplification)
    const float T999 = scan_val(1000);
    const float th0  = uu * T999;                // bit-identical th
    int idx = count_below(th0);

    const float V0 = logf(1e-7f);                // EPS/C
    const float V1 = logf(0.9999f + 1e-7f);      // (1-EPS) + EPS/C
    vfloat4* o4 = reinterpret_cast<vfloat4*>(out + (size_t)row * NCLS);
    #pragma unroll
    for (int t = 0; t < 4; ++t) {
        const int j = lane + 64 * t;
        if (j < NF4) {
            vfloat4 ov = {V0, V0, V0, V0};
            const int base = 4 * j;
            if (idx >= base && idx < base + 4)
                ov[idx - base] = V1;
            __builtin_nontemporal_store(ov, &o4[j]);
        }
    }

    // ---- fast-path verification: decide K==0 (margin ~2x) ----
    const float K6 = 0.2404491734814939f;        // log2(e)/6
    float mA = NEG, sA = 0.f;
    #pragma unroll
    for (int t = 0; t < 4; ++t) {
        mA = fmaxf(mA, fmaxf(fmaxf(lv[t][0], lv[t][1]), fmaxf(lv[t][2], lv[t][3])));
        sA += (fast_exp2(lv[t][0] * K6) + fast_exp2(lv[t][1] * K6))
            + (fast_exp2(lv[t][2] * K6) + fast_exp2(lv[t][3] * K6));
    }
    const float m1 = wave_max(mA);               // independent shfl chains
    const float s1 = wave_sum(sA);
    const float mc = fast_exp2(m1 * K6) / s1;    // max softmax#1 prob
    const float sd = fmaf(0.6f, mc * mc, 0.3f);

    const float L2E = 1.4426950408889634f;
    float m2l = NEG, s2l = 0.f;
    #pragma unroll
    for (int t = 0; t < 4; ++t) {
        const float y0 = fmaf(nv[t][0], sd, lv[t][0] * (1.0f / 6.0f));
        const float y1 = fmaf(nv[t][1], sd, lv[t][1] * (1.0f / 6.0f));
        const float y2 = fmaf(nv[t][2], sd, lv[t][2] * (1.0f / 6.0f));
        const float y3 = fmaf(nv[t][3], sd, lv[t][3] * (1.0f / 6.0f));
        m2l = fmaxf(m2l, fmaxf(fmaxf(y0, y1), fmaxf(y2, y3)));
        s2l += (fast_exp2(y0 * L2E) + fast_exp2(y1 * L2E))
             + (fast_exp2(y2 * L2E) + fast_exp2(y3 * L2E));
    }
    const float m2  = wave_max(m2l);
    const float s2  = wave_sum(s2l);
    const float e2m = fast_exp2(m2 * L2E);       // overflow/NaN -> exact path

    // K==0 <=> max renorm prob <= 0.05; require maxp < 1/22 = 0.0455.
    // Data margin: maxp <= ~0.026. Boundary rows fall to the exact path.
    if (__builtin_expect(!(s2 > 22.0f * e2m), 0)) {
        // ---- exact reference-semantics path (wave-uniform; cold) ----
        const float m1x = m1 / 6.0f;             // max(l)/6 == max(l/6)
        float se1 = 0.f;
        #pragma unroll
        for (int t = 0; t < 4; ++t)
            se1 += expf(lv[t][0] / 6.0f - m1x) + expf(lv[t][1] / 6.0f - m1x)
                 + expf(lv[t][2] / 6.0f - m1x) + expf(lv[t][3] / 6.0f - m1x);
        const float s1x = wave_sum(se1);
        const float mcx = 1.0f / s1x;
        const float sdx = 0.3f + 0.6f * (mcx * mcx);

        float m2xl = NEG;
        #pragma unroll
        for (int t = 0; t < 4; ++t) {
            const float y0 = lv[t][0] / 6.0f + nv[t][0] * sdx;
            const float y1 = lv[t][1] / 6.0f + nv[t][1] * sdx;
            const float y2 = lv[t][2] / 6.0f + nv[t][2] * sdx;
            const float y3 = lv[t][3] / 6.0f + nv[t][3] * sdx;
            m2xl = fmaxf(m2xl, fmaxf(fmaxf(y0, y1), fmaxf(y2, y3)));
        }
        const float m2x = wave_max(m2xl);
        float se2 = 0.f;
        #pragma unroll
        for (int t = 0; t < 4; ++t)
            se2 += expf(lv[t][0] / 6.0f + nv[t][0] * sdx - m2x)
                 + expf(lv[t][1] / 6.0f + nv[t][1] * sdx - m2x)
                 + expf(lv[t][2] / 6.0f + nv[t][2] * sdx - m2x)
                 + expf(lv[t][3] / 6.0f + nv[t][3] * sdx - m2x);
        const float s2x = wave_sum(se2);
        float cs = 0.f;
        #pragma unroll
        for (int t = 0; t < 4; ++t)
            cs += fminf(expf(lv[t][0] / 6.0f + nv[t][0] * sdx - m2x) / s2x, 0.6f)
                + fminf(expf(lv[t][1] / 6.0f + nv[t][1] * sdx - m2x) / s2x, 0.6f)
                + fminf(expf(lv[t][2] / 6.0f + nv[t][2] * sdx - m2x) / s2x, 0.6f)
                + fminf(expf(lv[t][3] / 6.0f + nv[t][3] * sdx - m2x) / s2x, 0.6f);
        const float rsum = wave_sum(cs);
        int kls = 0;
        #pragma unroll
        for (int t = 0; t < 4; ++t) {
            const int j = lane + 64 * t;
            if (j < NF4) {
                const float yv[4] = {
                    lv[t][0] / 6.0f + nv[t][0] * sdx, lv[t][1] / 6.0f + nv[t][1] * sdx,
                    lv[t][2] / 6.0f + nv[t][2] * sdx, lv[t][3] / 6.0f + nv[t][3] * sdx };
                #pragma unroll
                for (int c = 0; c < 4; ++c) {
                    const float cl = fminf(expf(yv[c] - m2x) / s2x, 0.6f);
                    const int kk = (int)rintf((cl / rsum) * 10.0f);
                    kbuf[wid][4 * j + c] = (unsigned char)kk;
                    kls += kk;
                }
            }
        }
        const int K = wave_sumi(kls);
        int idx2;
        if (K == 0) {
            idx2 = count_below(th0);
        } else {
            asm volatile("s_waitcnt lgkmcnt(0)" ::: "memory");
            __builtin_amdgcn_wave_barrier();
            int cnt = 0;
            if (lane == 0) {
                const double tab[11] = {0.0, 0.1, 0.2, 0.3, 0.4, 0.5,
                                        0.6, 0.7, 0.8, 0.9, 1.0};
                double c = 0.0;
                for (int i = 0; i < NCLS; ++i) c += tab[kbuf[wid][i]];
                const double th = (double)uu * c;
                c = 0.0;
                for (int i = 0; i < NCLS; ++i) {
                    c += tab[kbuf[wid][i]];
                    cnt += (c < th) ? 1 : 0;
                }
            }
            idx2 = __shfl(cnt, 0);
        }
        // rewrite the row with the exact index
        #pragma unroll
        for (int t = 0; t < 4; ++t) {
            const int j = lane + 64 * t;
            if (j < NF4) {
                vfloat4 ov = {V0, V0, V0, V0};
                const int base = 4 * j;
                if (idx2 >= base && idx2 < base + 4)
                    ov[idx2 - base] = V1;
                __builtin_nontemporal_store(ov, &o4[j]);
            }
        }
    }
}

extern "C" void kernel_launch(void* const* d_in, const int* in_sizes, int n_in,
                              void* d_out, int out_size, void* d_ws, size_t ws_size,
                              hipStream_t stream) {
    const float* logits = (const float*)d_in[0];
    const float* noise  = (const float*)d_in[1];
    const float* u      = (const float*)d_in[2];
    float* out = (float*)d_out;

    const int batch = in_sizes[2];       // 32768 rows (u is [B,1])
    const int blocks = (batch + WPB - 1) / WPB;

    hipLaunchKernelGGL(defence_kernel, dim3(blocks), dim3(TPB), 0, stream,
                       logits, noise, u, out, batch);
}